// Round 11
// baseline (220.106 us; speedup 1.0000x reference)
//
#include <hip/hip_runtime.h>
#include <cstdint>
#include <cstddef>

#define DI __device__ __forceinline__

typedef unsigned short u16;
typedef short bf16x8 __attribute__((ext_vector_type(8)));
typedef unsigned short u16x8 __attribute__((ext_vector_type(8)));
typedef float f32x4 __attribute__((ext_vector_type(4)));

static constexpr int DMODEL = 1024, T = 2048, BB = 4, NH = 16, HD = 64;
static constexpr int M = BB * T; // 8192

// workspace offsets in u16 elements
static constexpr size_t XB_OFF = 0;                                  // x bf16 [8192][1024]
static constexpr size_t WT_OFF = (size_t)M * DMODEL;                 // 4 x WtT bf16 [1024][1024]
static constexpr size_t Q_OFF  = WT_OFF + 4ull * DMODEL * DMODEL;    // Q [B,H,T,64]
static constexpr size_t K_OFF  = Q_OFF + (size_t)M * DMODEL;
static constexpr size_t V_OFF  = K_OFF + (size_t)M * DMODEL;
static constexpr size_t O_OFF  = XB_OFF;                             // attn out aliases xb

DI u16 f2bf(float x) {
  unsigned int u = __builtin_bit_cast(unsigned int, x);
  u += 0x7fffu + ((u >> 16) & 1u);
  return (u16)(u >> 16);
}

DI unsigned int cvtpk_bf16(float a, float b) {
  unsigned int r;
  asm("v_cvt_pk_bf16_f32 %0, %1, %2" : "=v"(r) : "v"(a), "v"(b));
  return r;
}

DI void gld_lds16(const void* g, void* l) {
  __builtin_amdgcn_global_load_lds(
      (const __attribute__((address_space(1))) void*)g,
      (__attribute__((address_space(3))) void*)l, 16, 0, 0);
}

// ---------------- cast x fp32 -> bf16 ----------------
__global__ void k_cast(const float* __restrict__ in, u16* __restrict__ out) {
  size_t i = (size_t)(blockIdx.x * 256 + threadIdx.x) * 8;
  float4 a = *(const float4*)(in + i);
  float4 b = *(const float4*)(in + i + 4);
  u16x8 v;
  v[0] = f2bf(a.x); v[1] = f2bf(a.y); v[2] = f2bf(a.z); v[3] = f2bf(a.w);
  v[4] = f2bf(b.x); v[5] = f2bf(b.y); v[6] = f2bf(b.z); v[7] = f2bf(b.w);
  *(u16x8*)(out + i) = v;
}

// ---------------- transpose+cast weights: W[K][N] f32 -> Wt[N][K] bf16 ----------------
__global__ void k_transw(const float* __restrict__ Wq, const float* __restrict__ Wk,
                         const float* __restrict__ Wv, const float* __restrict__ Wo,
                         u16* __restrict__ WtBase) {
  __shared__ u16 tile[32][33];
  const int z = blockIdx.z;
  const float* W = z == 0 ? Wq : (z == 1 ? Wk : (z == 2 ? Wv : Wo));
  u16* Wt = WtBase + (size_t)z * DMODEL * DMODEL;
  int tx = threadIdx.x, ty = threadIdx.y;
  int c = blockIdx.x * 32 + tx;
#pragma unroll
  for (int i = 0; i < 4; ++i) {
    int r = blockIdx.y * 32 + ty + i * 8;
    tile[ty + i * 8][tx] = f2bf(W[(size_t)r * DMODEL + c]);
  }
  __syncthreads();
#pragma unroll
  for (int i = 0; i < 4; ++i) {
    int rw = blockIdx.x * 32 + ty + i * 8;
    Wt[(size_t)rw * DMODEL + blockIdx.y * 32 + tx] = tile[tx][ty + i * 8];
  }
}

// ---------------- QKV projection GEMM: C = x @ W + b (bf16 MFMA, 128x128 tile, BK=64) ----
__launch_bounds__(256, 2)
__global__ void k_gemm_qkv(const u16* __restrict__ A, const u16* __restrict__ Wt,
                           const float* __restrict__ bq, const float* __restrict__ bk,
                           const float* __restrict__ bv,
                           u16* __restrict__ Qo, u16* __restrict__ Ko, u16* __restrict__ Vo) {
  __shared__ u16 As[128 * 64];
  __shared__ u16 Bs[128 * 64];
  const int z = blockIdx.z;
  const u16* Bt = Wt + (size_t)z * DMODEL * DMODEL;
  const float* bias = z == 0 ? bq : (z == 1 ? bk : bv);
  u16* out = z == 0 ? Qo : (z == 1 ? Ko : Vo);
  // Q gets 1/sqrt(Hd) * log2(e) folded in so softmax can use exp2
  const float scale = z == 0 ? 0.125f * 1.4426950408889634f : 1.0f;

  const int tid = threadIdx.x;
  const int wave = tid >> 6, lane = tid & 63;
  const int g = lane >> 4, l15 = lane & 15;
  const int brow = blockIdx.x * 128, bcol = blockIdx.y * 128;
  const int wr = wave >> 1, wc = wave & 1;
  const int srow = tid >> 3, schunk = tid & 7;

  f32x4 acc[4][4] = {};

  for (int k0 = 0; k0 < DMODEL; k0 += 64) {
    __syncthreads();
#pragma unroll
    for (int j = 0; j < 4; ++j) {
      int r = j * 32 + srow;
      int cs = (schunk ^ (r & 7)) * 8;
      gld_lds16(A + (size_t)(brow + r) * DMODEL + k0 + cs, (char*)As + j * 4096 + wave * 1024);
      gld_lds16(Bt + (size_t)(bcol + r) * DMODEL + k0 + cs, (char*)Bs + j * 4096 + wave * 1024);
    }
    __syncthreads();
#pragma unroll
    for (int kh = 0; kh < 2; ++kh) {
      bf16x8 af[4], bfr[4];
#pragma unroll
      for (int m = 0; m < 4; ++m) {
        int r = wr * 64 + m * 16 + l15;
        int ch = (kh * 4 + g) ^ (r & 7);
        af[m] = *(const bf16x8*)((const char*)As + r * 128 + ch * 16);
      }
#pragma unroll
      for (int n = 0; n < 4; ++n) {
        int r = wc * 64 + n * 16 + l15;
        int ch = (kh * 4 + g) ^ (r & 7);
        bfr[n] = *(const bf16x8*)((const char*)Bs + r * 128 + ch * 16);
      }
#pragma unroll
      for (int m = 0; m < 4; ++m)
#pragma unroll
        for (int n = 0; n < 4; ++n)
          acc[m][n] = __builtin_amdgcn_mfma_f32_16x16x32_bf16(af[m], bfr[n], acc[m][n], 0, 0, 0);
    }
  }

#pragma unroll
  for (int m = 0; m < 4; ++m)
#pragma unroll
    for (int n = 0; n < 4; ++n) {
      int col = bcol + wc * 64 + n * 16 + l15;
      float bias_v = bias[col];
      int h = col >> 6, d = col & 63;
#pragma unroll
      for (int r = 0; r < 4; ++r) {
        int row = brow + wr * 64 + m * 16 + g * 4 + r;
        int b = row >> 11, t = row & 2047;
        float v = (acc[m][n][r] + bias_v) * scale;
        out[(((size_t)(b * NH + h) * T + t) << 6) + d] = f2bf(v);
      }
    }
}

// ---------------- output projection GEMM: out = O @ Wo + bo (fp32 out) ----------------
__launch_bounds__(256, 2)
__global__ void k_gemm_out(const u16* __restrict__ A, const u16* __restrict__ Bt,
                           const float* __restrict__ bias, float* __restrict__ out) {
  __shared__ u16 As[128 * 64];
  __shared__ u16 Bs[128 * 64];
  const int tid = threadIdx.x;
  const int wave = tid >> 6, lane = tid & 63;
  const int g = lane >> 4, l15 = lane & 15;
  const int brow = blockIdx.x * 128, bcol = blockIdx.y * 128;
  const int wr = wave >> 1, wc = wave & 1;
  const int srow = tid >> 3, schunk = tid & 7;

  f32x4 acc[4][4] = {};

  for (int k0 = 0; k0 < DMODEL; k0 += 64) {
    __syncthreads();
#pragma unroll
    for (int j = 0; j < 4; ++j) {
      int r = j * 32 + srow;
      int cs = (schunk ^ (r & 7)) * 8;
      gld_lds16(A + (size_t)(brow + r) * DMODEL + k0 + cs, (char*)As + j * 4096 + wave * 1024);
      gld_lds16(Bt + (size_t)(bcol + r) * DMODEL + k0 + cs, (char*)Bs + j * 4096 + wave * 1024);
    }
    __syncthreads();
#pragma unroll
    for (int kh = 0; kh < 2; ++kh) {
      bf16x8 af[4], bfr[4];
#pragma unroll
      for (int m = 0; m < 4; ++m) {
        int r = wr * 64 + m * 16 + l15;
        int ch = (kh * 4 + g) ^ (r & 7);
        af[m] = *(const bf16x8*)((const char*)As + r * 128 + ch * 16);
      }
#pragma unroll
      for (int n = 0; n < 4; ++n) {
        int r = wc * 64 + n * 16 + l15;
        int ch = (kh * 4 + g) ^ (r & 7);
        bfr[n] = *(const bf16x8*)((const char*)Bs + r * 128 + ch * 16);
      }
#pragma unroll
      for (int m = 0; m < 4; ++m)
#pragma unroll
        for (int n = 0; n < 4; ++n)
          acc[m][n] = __builtin_amdgcn_mfma_f32_16x16x32_bf16(af[m], bfr[n], acc[m][n], 0, 0, 0);
    }
  }

#pragma unroll
  for (int m = 0; m < 4; ++m)
#pragma unroll
    for (int n = 0; n < 4; ++n) {
      int col = bcol + wc * 64 + n * 16 + l15;
      float bias_v = bias[col];
#pragma unroll
      for (int r = 0; r < 4; ++r) {
        int row = brow + wr * 64 + m * 16 + g * 4 + r;
        out[(size_t)row * DMODEL + col] = acc[m][n][r] + bias_v;
      }
    }
}

// ---------------- causal flash attention (O^T form, in-register P, dbuf K+V) ------------
// grid (32, 64): x -> q-tile (big-first: qt = 31-bx), y = b*16+h. ONE q-tile per block.
// block 256 = 4 waves x 16 q-rows; KV tiles of 64.
// K staged via global_load_lds (DMA), double-buffered; V reg-staged transposed
// (v_perm_b32 packing), double-buffered. ONE barrier per tile.
// S^T = mfma(K_perm, Q) with tau(l15) (swap bits 2<->3) so the P^T B-frag for
// O^T = mfma(V^T, P^T) is 4 cvt_pk + 2 permlane32_swap per kvh. Row state lane-local.
// Max reduce via __shfl_xor; sum reduce deferred to the epilogue. T13 defer-max.
// Ot ALIASES Ks (epilogue-only use, barrier-fenced) -> LDS 32 KB -> 5 blocks/CU
// (was 40 KB -> 4). launch_bounds (256,4): VGPR cap 128, actual 64 -> no spills,
// occupancy limited by LDS at 5 blocks = 20 waves/CU.
__launch_bounds__(256, 4)
__global__ void k_attn(const u16* __restrict__ Qw, const u16* __restrict__ Kw,
                       const u16* __restrict__ Vw, u16* __restrict__ Ow) {
  __shared__ u16 Ks[2][64 * 64];   // 16 KB (epilogue Ot aliases this)
  __shared__ u16 Vt[2][64 * 64];   // 16 KB

  const int tid = threadIdx.x;
  const int wave = tid >> 6, lane = tid & 63;
  const int g = lane >> 4, l15 = lane & 15;
  const int tl = (l15 & 3) | ((l15 & 4) << 1) | ((l15 & 8) >> 1);  // swap bits 2,3
  const int qt = 31 - blockIdx.x;   // heavy tiles dispatched first
  const int bh = blockIdx.y;
  const u16* Qb = Qw + (size_t)bh * T * HD;
  const u16* Kb = Kw + (size_t)bh * T * HD;
  const u16* Vb = Vw + (size_t)bh * T * HD;
  const int b = bh >> 4, h = bh & 15;
  const int vp = tid & 31, vcg = tid >> 5;
  const int krow = tid >> 3, kchunk = tid & 7;  // K staging: row, 16B-chunk

  const int ntiles = qt + 1;

  // Q (B-operand) frags; Q pre-scaled by 1/8*log2e
  bf16x8 qf[2];
  {
    int qrow = qt * 64 + wave * 16 + l15;
#pragma unroll
    for (int kh = 0; kh < 2; ++kh)
      qf[kh] = *(const bf16x8*)(Qb + (size_t)qrow * HD + kh * 32 + g * 8);
  }

  f32x4 oacc[4] = {};
  float mrun = -1e30f, lrun = 0.f;  // lrun is a LANE-LOCAL partial sum

  // prologue: V[0] reg loads first (counted waits), then K[0] DMA
  {
    const u16* gv = Vb + (size_t)(2 * vp) * HD + vcg * 8;
    bf16x8 v0 = *(const bf16x8*)gv;
    bf16x8 v1 = *(const bf16x8*)(gv + HD);
#pragma unroll
    for (int j = 0; j < 2; ++j) {
      int r = j * 32 + krow;
      gld_lds16(Kb + (size_t)r * HD + (kchunk ^ (r & 7)) * 8,
                (char*)(Ks[0]) + j * 4096 + wave * 1024);
    }
    char* vtb = (char*)(Vt[0]);
    const unsigned int* w0 = (const unsigned int*)&v0;
    const unsigned int* w1 = (const unsigned int*)&v1;
#pragma unroll
    for (int d2 = 0; d2 < 4; ++d2) {
      int c0 = vcg * 8 + 2 * d2, c1 = c0 + 1;
      unsigned int pk0 = __builtin_amdgcn_perm(w1[d2], w0[d2], 0x05040100u);
      unsigned int pk1 = __builtin_amdgcn_perm(w1[d2], w0[d2], 0x07060302u);
      *(unsigned int*)(vtb + ((c0 * 128 + 4 * vp) ^ ((c0 & 7) << 4))) = pk0;
      *(unsigned int*)(vtb + ((c1 * 128 + 4 * vp) ^ ((c1 & 7) << 4))) = pk1;
    }
  }

  for (int kt = 0; kt < ntiles; ++kt) {
    __syncthreads();  // drains vmcnt+lgkm: K DMA + V writes for tile kt visible
    const int cur = kt & 1;
    const bool havenext = (kt + 1 < ntiles);

    // prefetch next V tile into regs (issued first -> counted vmcnt at use)
    bf16x8 v0, v1;
    if (havenext) {
      const u16* gv = Vb + (size_t)((kt + 1) * 64 + 2 * vp) * HD + vcg * 8;
      v0 = *(const bf16x8*)gv;
      v1 = *(const bf16x8*)(gv + HD);
      // issue next K stage (DMA into other buffer; overlaps this tile's compute)
#pragma unroll
      for (int j = 0; j < 2; ++j) {
        int r = j * 32 + krow;
        gld_lds16(Kb + (size_t)((kt + 1) * 64 + r) * HD + (kchunk ^ (r & 7)) * 8,
                  (char*)(Ks[cur ^ 1]) + j * 4096 + wave * 1024);
      }
    }

    // K frags (A-operand) from LDS, rows permuted by tau
    bf16x8 kf[2][4];
#pragma unroll
    for (int kh = 0; kh < 2; ++kh)
#pragma unroll
      for (int n = 0; n < 4; ++n) {
        int rr = n * 16 + tl;
        int ch = (kh * 4 + g) ^ (rr & 7);
        kf[kh][n] = *(const bf16x8*)((const char*)(Ks[cur]) + rr * 128 + ch * 16);
      }

    // S^T = K Q^T
    f32x4 s[4] = {};
    __builtin_amdgcn_s_setprio(1);
#pragma unroll
    for (int kh = 0; kh < 2; ++kh)
#pragma unroll
      for (int n = 0; n < 4; ++n)
        s[n] = __builtin_amdgcn_mfma_f32_16x16x32_bf16(kf[kh][n], qf[kh], s[n], 0, 0, 0);
    __builtin_amdgcn_s_setprio(0);

    // causal mask (diagonal tile only); kv_in accounts for the tau permutation
    if (kt == qt) {
      int q_in = wave * 16 + l15;
#pragma unroll
      for (int n = 0; n < 4; ++n)
#pragma unroll
        for (int r = 0; r < 4; ++r) {
          int kv_in = n * 16 + (g & 1) * 8 + (g >> 1) * 4 + r;
          if (kv_in > q_in) s[n][r] = -1e30f;
        }
    }

    // lane-local online softmax (row q = l15; base-2), max3-friendly tree
    float t0 = fmaxf(fmaxf(s[0][0], s[0][1]), s[0][2]);
    float t1 = fmaxf(fmaxf(s[0][3], s[1][0]), s[1][1]);
    float t2 = fmaxf(fmaxf(s[1][2], s[1][3]), s[2][0]);
    float t3 = fmaxf(fmaxf(s[2][1], s[2][2]), s[2][3]);
    float t4 = fmaxf(fmaxf(s[3][0], s[3][1]), s[3][2]);
    float vmax = fmaxf(fmaxf(fmaxf(t0, t1), t2), fmaxf(fmaxf(t3, t4), s[3][3]));
    vmax = fmaxf(vmax, __shfl_xor(vmax, 16));
    vmax = fmaxf(vmax, __shfl_xor(vmax, 32));

    // T13 defer-max: only rescale when the row max grew by > 8 (base-2 units)
    if (!__all(vmax - mrun <= 8.f)) {
      float mnew = fmaxf(mrun, vmax);
      float a = exp2f(mrun - mnew);
      lrun *= a;
#pragma unroll
      for (int n = 0; n < 4; ++n)
#pragma unroll
        for (int r = 0; r < 4; ++r) oacc[n][r] *= a;
      mrun = mnew;
    }

    // P = exp2(S - m); accumulate lane-local partial sum (4-way split chains);
    // NO per-tile cross-lane sum -- deferred to the epilogue.
    float ps0 = 0.f, ps1 = 0.f, ps2 = 0.f, ps3 = 0.f;
#pragma unroll
    for (int n = 0; n < 4; ++n) {
      float p0 = exp2f(s[n][0] - mrun);
      float p1 = exp2f(s[n][1] - mrun);
      float p2 = exp2f(s[n][2] - mrun);
      float p3 = exp2f(s[n][3] - mrun);
      s[n][0] = p0; s[n][1] = p1; s[n][2] = p2; s[n][3] = p3;
      ps0 += p0; ps1 += p1; ps2 += p2; ps3 += p3;
    }
    lrun += (ps0 + ps1) + (ps2 + ps3);

    // O^T += V^T P^T : B-frag via cvt_pk + permlane32_swap, A-frag from Vt[cur]
    __builtin_amdgcn_s_setprio(1);
#pragma unroll
    for (int kvh = 0; kvh < 2; ++kvh) {
      const int nlo = kvh * 2, nhi = kvh * 2 + 1;
      unsigned int L0 = cvtpk_bf16(s[nlo][0], s[nlo][1]);
      unsigned int L1 = cvtpk_bf16(s[nlo][2], s[nlo][3]);
      unsigned int H0 = cvtpk_bf16(s[nhi][0], s[nhi][1]);
      unsigned int H1 = cvtpk_bf16(s[nhi][2], s[nhi][3]);
      asm volatile("v_permlane32_swap_b32 %0, %1" : "+v"(L0), "+v"(H0));
      asm volatile("v_permlane32_swap_b32 %0, %1" : "+v"(L1), "+v"(H1));
      bf16x8 pb;
      unsigned int* pw = (unsigned int*)&pb;
      pw[0] = L0; pw[1] = L1; pw[2] = H0; pw[3] = H1;

      const int ch = ((kvh * 4 + g) ^ (l15 & 7)) * 16;
#pragma unroll
      for (int n = 0; n < 4; ++n) {
        bf16x8 an = *(const bf16x8*)((const char*)(Vt[cur]) + (n * 16 + l15) * 128 + ch);
        oacc[n] = __builtin_amdgcn_mfma_f32_16x16x32_bf16(an, pb, oacc[n], 0, 0, 0);
      }
    }
    __builtin_amdgcn_s_setprio(0);

    // write prefetched V into the other buffer (perm-packed)
    if (havenext) {
      char* vtb = (char*)(Vt[cur ^ 1]);
      const unsigned int* w0 = (const unsigned int*)&v0;
      const unsigned int* w1 = (const unsigned int*)&v1;
#pragma unroll
      for (int d2 = 0; d2 < 4; ++d2) {
        int c0 = vcg * 8 + 2 * d2, c1 = c0 + 1;
        unsigned int pk0 = __builtin_amdgcn_perm(w1[d2], w0[d2], 0x05040100u);
        unsigned int pk1 = __builtin_amdgcn_perm(w1[d2], w0[d2], 0x07060302u);
        *(unsigned int*)(vtb + ((c0 * 128 + 4 * vp) ^ ((c0 & 7) << 4))) = pk0;
        *(unsigned int*)(vtb + ((c1 * 128 + 4 * vp) ^ ((c1 & 7) << 4))) = pk1;
      }
    }
  }

  // epilogue: finish deferred sum reduce, normalize, transpose O^T -> O via LDS
  // (Ot aliases Ks -- fence with barriers), coalesced store
  {
    float ltot = lrun;
    ltot += __shfl_xor(ltot, 16);
    ltot += __shfl_xor(ltot, 32);
    float inv = 1.f / ltot;
    __syncthreads();  // all waves done reading Ks/Vt before aliased Ot writes
    char* otb = (char*)Ks;
#pragma unroll
    for (int n = 0; n < 4; ++n)
#pragma unroll
      for (int i = 0; i < 2; ++i) {
        unsigned int w = cvtpk_bf16(oacc[n][2 * i] * inv, oacc[n][2 * i + 1] * inv);
        int didx = n * 8 + g * 2 + i;  // d-pair index (d = 2*didx)
        int off = (wave * 16 + l15) * 128 + ((didx * 4) ^ ((l15 & 7) << 4));
        *(unsigned int*)(otb + off) = w;
      }
    __syncthreads();
    int q = tid >> 2, seg = tid & 3;
    uint4 c0 = *(const uint4*)(otb + q * 128 + (((seg * 2) ^ (q & 7)) << 4));
    uint4 c1 = *(const uint4*)(otb + q * 128 + (((seg * 2 + 1) ^ (q & 7)) << 4));
    u16* dst = Ow + ((size_t)b * T + qt * 64 + q) * DMODEL + h * 64 + seg * 16;
    *(uint4*)dst = c0;
    *(uint4*)(dst + 8) = c1;
  }
}

extern "C" void kernel_launch(void* const* d_in, const int* in_sizes, int n_in,
                              void* d_out, int out_size, void* d_ws, size_t ws_size,
                              hipStream_t stream) {
  const float* x  = (const float*)d_in[0];
  const float* Wq = (const float*)d_in[1];
  const float* bq = (const float*)d_in[2];
  const float* Wk = (const float*)d_in[3];
  const float* bk = (const float*)d_in[4];
  const float* Wv = (const float*)d_in[5];
  const float* bv = (const float*)d_in[6];
  const float* Wo = (const float*)d_in[7];
  const float* bo = (const float*)d_in[8];
  float* out = (float*)d_out;
  u16* ws = (u16*)d_ws;

  // cast x to bf16: 8M elems, 8/thread
  k_cast<<<4096, 256, 0, stream>>>(x, ws + XB_OFF);
  // transpose+cast the 4 weights
  k_transw<<<dim3(32, 32, 4), dim3(32, 8), 0, stream>>>(Wq, Wk, Wv, Wo, ws + WT_OFF);
  // QKV projections (z = 0,1,2)
  k_gemm_qkv<<<dim3(64, 8, 3), 256, 0, stream>>>(ws + XB_OFF, ws + WT_OFF, bq, bk, bv,
                                                 ws + Q_OFF, ws + K_OFF, ws + V_OFF);
  // causal flash attention (single q-tile per block, big-first; 5 blocks/CU)
  k_attn<<<dim3(32, 64), 256, 0, stream>>>(ws + Q_OFF, ws + K_OFF, ws + V_OFF, ws + O_OFF);
  // output projection
  k_gemm_out<<<dim3(64, 8), 256, 0, stream>>>(ws + O_OFF, ws + WT_OFF + 3ull * DMODEL * DMODEL,
                                              bo, out);
}

// Round 12
// 165.120 us; speedup vs baseline: 1.3330x; 1.3330x over previous
//
#include <hip/hip_runtime.h>
#include <cstdint>
#include <cstddef>

#define DI __device__ __forceinline__

typedef unsigned short u16;
typedef short bf16x8 __attribute__((ext_vector_type(8)));
typedef unsigned short u16x8 __attribute__((ext_vector_type(8)));
typedef float f32x4 __attribute__((ext_vector_type(4)));

static constexpr int DMODEL = 1024, T = 2048, BB = 4, NH = 16, HD = 64;
static constexpr int M = BB * T; // 8192

// workspace offsets in u16 elements
static constexpr size_t XB_OFF = 0;                                  // x bf16 [8192][1024]
static constexpr size_t WT_OFF = (size_t)M * DMODEL;                 // 4 x WtT bf16 [1024][1024]
static constexpr size_t Q_OFF  = WT_OFF + 4ull * DMODEL * DMODEL;    // Q [B,H,T,64]
static constexpr size_t K_OFF  = Q_OFF + (size_t)M * DMODEL;
static constexpr size_t V_OFF  = K_OFF + (size_t)M * DMODEL;
static constexpr size_t O_OFF  = XB_OFF;                             // attn out aliases xb

DI u16 f2bf(float x) {
  unsigned int u = __builtin_bit_cast(unsigned int, x);
  u += 0x7fffu + ((u >> 16) & 1u);
  return (u16)(u >> 16);
}

DI unsigned int cvtpk_bf16(float a, float b) {
  unsigned int r;
  asm("v_cvt_pk_bf16_f32 %0, %1, %2" : "=v"(r) : "v"(a), "v"(b));
  return r;
}

DI void gld_lds16(const void* g, void* l) {
  __builtin_amdgcn_global_load_lds(
      (const __attribute__((address_space(1))) void*)g,
      (__attribute__((address_space(3))) void*)l, 16, 0, 0);
}

// ---------------- cast x fp32 -> bf16 ----------------
__global__ void k_cast(const float* __restrict__ in, u16* __restrict__ out) {
  size_t i = (size_t)(blockIdx.x * 256 + threadIdx.x) * 8;
  float4 a = *(const float4*)(in + i);
  float4 b = *(const float4*)(in + i + 4);
  u16x8 v;
  v[0] = f2bf(a.x); v[1] = f2bf(a.y); v[2] = f2bf(a.z); v[3] = f2bf(a.w);
  v[4] = f2bf(b.x); v[5] = f2bf(b.y); v[6] = f2bf(b.z); v[7] = f2bf(b.w);
  *(u16x8*)(out + i) = v;
}

// ---------------- transpose+cast weights: W[K][N] f32 -> Wt[N][K] bf16 ----------------
__global__ void k_transw(const float* __restrict__ Wq, const float* __restrict__ Wk,
                         const float* __restrict__ Wv, const float* __restrict__ Wo,
                         u16* __restrict__ WtBase) {
  __shared__ u16 tile[32][33];
  const int z = blockIdx.z;
  const float* W = z == 0 ? Wq : (z == 1 ? Wk : (z == 2 ? Wv : Wo));
  u16* Wt = WtBase + (size_t)z * DMODEL * DMODEL;
  int tx = threadIdx.x, ty = threadIdx.y;
  int c = blockIdx.x * 32 + tx;
#pragma unroll
  for (int i = 0; i < 4; ++i) {
    int r = blockIdx.y * 32 + ty + i * 8;
    tile[ty + i * 8][tx] = f2bf(W[(size_t)r * DMODEL + c]);
  }
  __syncthreads();
#pragma unroll
  for (int i = 0; i < 4; ++i) {
    int rw = blockIdx.x * 32 + ty + i * 8;
    Wt[(size_t)rw * DMODEL + blockIdx.y * 32 + tx] = tile[tx][ty + i * 8];
  }
}

// ---------------- QKV projection GEMM: C = x @ W + b (bf16 MFMA, 128x128 tile, BK=64) ----
__launch_bounds__(256, 2)
__global__ void k_gemm_qkv(const u16* __restrict__ A, const u16* __restrict__ Wt,
                           const float* __restrict__ bq, const float* __restrict__ bk,
                           const float* __restrict__ bv,
                           u16* __restrict__ Qo, u16* __restrict__ Ko, u16* __restrict__ Vo) {
  __shared__ u16 As[128 * 64];
  __shared__ u16 Bs[128 * 64];
  const int z = blockIdx.z;
  const u16* Bt = Wt + (size_t)z * DMODEL * DMODEL;
  const float* bias = z == 0 ? bq : (z == 1 ? bk : bv);
  u16* out = z == 0 ? Qo : (z == 1 ? Ko : Vo);
  // Q gets 1/sqrt(Hd) * log2(e) folded in so softmax can use exp2
  const float scale = z == 0 ? 0.125f * 1.4426950408889634f : 1.0f;

  const int tid = threadIdx.x;
  const int wave = tid >> 6, lane = tid & 63;
  const int g = lane >> 4, l15 = lane & 15;
  const int brow = blockIdx.x * 128, bcol = blockIdx.y * 128;
  const int wr = wave >> 1, wc = wave & 1;
  const int srow = tid >> 3, schunk = tid & 7;

  f32x4 acc[4][4] = {};

  for (int k0 = 0; k0 < DMODEL; k0 += 64) {
    __syncthreads();
#pragma unroll
    for (int j = 0; j < 4; ++j) {
      int r = j * 32 + srow;
      int cs = (schunk ^ (r & 7)) * 8;
      gld_lds16(A + (size_t)(brow + r) * DMODEL + k0 + cs, (char*)As + j * 4096 + wave * 1024);
      gld_lds16(Bt + (size_t)(bcol + r) * DMODEL + k0 + cs, (char*)Bs + j * 4096 + wave * 1024);
    }
    __syncthreads();
#pragma unroll
    for (int kh = 0; kh < 2; ++kh) {
      bf16x8 af[4], bfr[4];
#pragma unroll
      for (int m = 0; m < 4; ++m) {
        int r = wr * 64 + m * 16 + l15;
        int ch = (kh * 4 + g) ^ (r & 7);
        af[m] = *(const bf16x8*)((const char*)As + r * 128 + ch * 16);
      }
#pragma unroll
      for (int n = 0; n < 4; ++n) {
        int r = wc * 64 + n * 16 + l15;
        int ch = (kh * 4 + g) ^ (r & 7);
        bfr[n] = *(const bf16x8*)((const char*)Bs + r * 128 + ch * 16);
      }
#pragma unroll
      for (int m = 0; m < 4; ++m)
#pragma unroll
        for (int n = 0; n < 4; ++n)
          acc[m][n] = __builtin_amdgcn_mfma_f32_16x16x32_bf16(af[m], bfr[n], acc[m][n], 0, 0, 0);
    }
  }

#pragma unroll
  for (int m = 0; m < 4; ++m)
#pragma unroll
    for (int n = 0; n < 4; ++n) {
      int col = bcol + wc * 64 + n * 16 + l15;
      float bias_v = bias[col];
      int h = col >> 6, d = col & 63;
#pragma unroll
      for (int r = 0; r < 4; ++r) {
        int row = brow + wr * 64 + m * 16 + g * 4 + r;
        int b = row >> 11, t = row & 2047;
        float v = (acc[m][n][r] + bias_v) * scale;
        out[(((size_t)(b * NH + h) * T + t) << 6) + d] = f2bf(v);
      }
    }
}

// ---------------- output projection GEMM: out = O @ Wo + bo (fp32 out) ----------------
__launch_bounds__(256, 2)
__global__ void k_gemm_out(const u16* __restrict__ A, const u16* __restrict__ Bt,
                           const float* __restrict__ bias, float* __restrict__ out) {
  __shared__ u16 As[128 * 64];
  __shared__ u16 Bs[128 * 64];
  const int tid = threadIdx.x;
  const int wave = tid >> 6, lane = tid & 63;
  const int g = lane >> 4, l15 = lane & 15;
  const int brow = blockIdx.x * 128, bcol = blockIdx.y * 128;
  const int wr = wave >> 1, wc = wave & 1;
  const int srow = tid >> 3, schunk = tid & 7;

  f32x4 acc[4][4] = {};

  for (int k0 = 0; k0 < DMODEL; k0 += 64) {
    __syncthreads();
#pragma unroll
    for (int j = 0; j < 4; ++j) {
      int r = j * 32 + srow;
      int cs = (schunk ^ (r & 7)) * 8;
      gld_lds16(A + (size_t)(brow + r) * DMODEL + k0 + cs, (char*)As + j * 4096 + wave * 1024);
      gld_lds16(Bt + (size_t)(bcol + r) * DMODEL + k0 + cs, (char*)Bs + j * 4096 + wave * 1024);
    }
    __syncthreads();
#pragma unroll
    for (int kh = 0; kh < 2; ++kh) {
      bf16x8 af[4], bfr[4];
#pragma unroll
      for (int m = 0; m < 4; ++m) {
        int r = wr * 64 + m * 16 + l15;
        int ch = (kh * 4 + g) ^ (r & 7);
        af[m] = *(const bf16x8*)((const char*)As + r * 128 + ch * 16);
      }
#pragma unroll
      for (int n = 0; n < 4; ++n) {
        int r = wc * 64 + n * 16 + l15;
        int ch = (kh * 4 + g) ^ (r & 7);
        bfr[n] = *(const bf16x8*)((const char*)Bs + r * 128 + ch * 16);
      }
#pragma unroll
      for (int m = 0; m < 4; ++m)
#pragma unroll
        for (int n = 0; n < 4; ++n)
          acc[m][n] = __builtin_amdgcn_mfma_f32_16x16x32_bf16(af[m], bfr[n], acc[m][n], 0, 0, 0);
    }
  }

#pragma unroll
  for (int m = 0; m < 4; ++m)
#pragma unroll
    for (int n = 0; n < 4; ++n) {
      int col = bcol + wc * 64 + n * 16 + l15;
      float bias_v = bias[col];
#pragma unroll
      for (int r = 0; r < 4; ++r) {
        int row = brow + wr * 64 + m * 16 + g * 4 + r;
        out[(size_t)row * DMODEL + col] = acc[m][n][r] + bias_v;
      }
    }
}

// ---------------- causal flash attention (O^T form, in-register P, dbuf K+V) ------------
// grid: 1024 blocks 1-D, XCD-swizzled: l -> xcd = l&7, w = l>>3,
//   bh = xcd + (w&7)*8, qp = w>>3.  All 16 blocks of a head land on ONE XCD
//   (assuming round-robin blockIdx->XCD), so each XCD's L2 holds 8 heads' KV
//   (8 x 512 KB = 4 MB = L2 size). R11 showed the default mapping causes ~8x
//   KV over-fetch (FETCH 194 MB vs ~55 ideal).
// Paired q-tiles {31-qp, qp} = 33 KV tiles per block (uniform cost, zero tail).
// block 256 = 4 waves x 16 q-rows; KV tiles of 64.
// K staged via global_load_lds (DMA), double-buffered; V reg-staged transposed
// (v_perm_b32 packing), double-buffered. ONE barrier per tile.
// S^T = mfma(K_perm, Q) with tau(l15) (swap bits 2<->3) so the P^T B-frag for
// O^T = mfma(V^T, P^T) is 4 cvt_pk + 2 permlane32_swap per kvh. Row state lane-local.
// Max reduce via __shfl_xor; sum reduce deferred to the epilogue. T13 defer-max.
// launch_bounds (256,4): VGPR cap 128, actual ~64 -> no spills. LDS 40 KB -> 4/CU.
__launch_bounds__(256, 4)
__global__ void k_attn(const u16* __restrict__ Qw, const u16* __restrict__ Kw,
                       const u16* __restrict__ Vw, u16* __restrict__ Ow) {
  __shared__ u16 Ks[2][64 * 64];   // 16 KB
  __shared__ u16 Vt[2][64 * 64];   // 16 KB
  __shared__ u16 Ot[64 * 64];      // 8 KB

  const int tid = threadIdx.x;
  const int wave = tid >> 6, lane = tid & 63;
  const int g = lane >> 4, l15 = lane & 15;
  const int tl = (l15 & 3) | ((l15 & 4) << 1) | ((l15 & 8) >> 1);  // swap bits 2,3
  // XCD-locality swizzle (bijective on 1024)
  const int l = blockIdx.x;
  const int xcd = l & 7, w = l >> 3;
  const int bh = xcd + ((w & 7) << 3);
  const int qp = w >> 3;
  const u16* Qb = Qw + (size_t)bh * T * HD;
  const u16* Kb = Kw + (size_t)bh * T * HD;
  const u16* Vb = Vw + (size_t)bh * T * HD;
  const int b = bh >> 4, h = bh & 15;
  const int vp = tid & 31, vcg = tid >> 5;
  const int krow = tid >> 3, kchunk = tid & 7;  // K staging: row, 16B-chunk

  for (int half = 0; half < 2; ++half) {
    const int qt = half == 0 ? (31 - qp) : qp;
    const int ntiles = qt + 1;

    // Q (B-operand) frags; Q pre-scaled by 1/8*log2e
    bf16x8 qf[2];
    {
      int qrow = qt * 64 + wave * 16 + l15;
#pragma unroll
      for (int kh = 0; kh < 2; ++kh)
        qf[kh] = *(const bf16x8*)(Qb + (size_t)qrow * HD + kh * 32 + g * 8);
    }

    f32x4 oacc[4] = {};
    float mrun = -1e30f, lrun = 0.f;  // lrun is a LANE-LOCAL partial sum

    // prologue: V[0] reg loads first (counted waits), then K[0] DMA
    {
      const u16* gv = Vb + (size_t)(2 * vp) * HD + vcg * 8;
      bf16x8 v0 = *(const bf16x8*)gv;
      bf16x8 v1 = *(const bf16x8*)(gv + HD);
#pragma unroll
      for (int j = 0; j < 2; ++j) {
        int r = j * 32 + krow;
        gld_lds16(Kb + (size_t)r * HD + (kchunk ^ (r & 7)) * 8,
                  (char*)(Ks[0]) + j * 4096 + wave * 1024);
      }
      char* vtb = (char*)(Vt[0]);
      const unsigned int* w0 = (const unsigned int*)&v0;
      const unsigned int* w1 = (const unsigned int*)&v1;
#pragma unroll
      for (int d2 = 0; d2 < 4; ++d2) {
        int c0 = vcg * 8 + 2 * d2, c1 = c0 + 1;
        unsigned int pk0 = __builtin_amdgcn_perm(w1[d2], w0[d2], 0x05040100u);
        unsigned int pk1 = __builtin_amdgcn_perm(w1[d2], w0[d2], 0x07060302u);
        *(unsigned int*)(vtb + ((c0 * 128 + 4 * vp) ^ ((c0 & 7) << 4))) = pk0;
        *(unsigned int*)(vtb + ((c1 * 128 + 4 * vp) ^ ((c1 & 7) << 4))) = pk1;
      }
    }

    for (int kt = 0; kt < ntiles; ++kt) {
      __syncthreads();  // drains vmcnt+lgkm: K DMA + V writes for tile kt visible
      const int cur = kt & 1;
      const bool havenext = (kt + 1 < ntiles);

      // prefetch next V tile into regs (issued first -> counted vmcnt at use)
      bf16x8 v0, v1;
      if (havenext) {
        const u16* gv = Vb + (size_t)((kt + 1) * 64 + 2 * vp) * HD + vcg * 8;
        v0 = *(const bf16x8*)gv;
        v1 = *(const bf16x8*)(gv + HD);
        // issue next K stage (DMA into other buffer; overlaps this tile's compute)
#pragma unroll
        for (int j = 0; j < 2; ++j) {
          int r = j * 32 + krow;
          gld_lds16(Kb + (size_t)((kt + 1) * 64 + r) * HD + (kchunk ^ (r & 7)) * 8,
                    (char*)(Ks[cur ^ 1]) + j * 4096 + wave * 1024);
        }
      }

      // K frags (A-operand) from LDS, rows permuted by tau
      bf16x8 kf[2][4];
#pragma unroll
      for (int kh = 0; kh < 2; ++kh)
#pragma unroll
        for (int n = 0; n < 4; ++n) {
          int rr = n * 16 + tl;
          int ch = (kh * 4 + g) ^ (rr & 7);
          kf[kh][n] = *(const bf16x8*)((const char*)(Ks[cur]) + rr * 128 + ch * 16);
        }

      // S^T = K Q^T
      f32x4 s[4] = {};
      __builtin_amdgcn_s_setprio(1);
#pragma unroll
      for (int kh = 0; kh < 2; ++kh)
#pragma unroll
        for (int n = 0; n < 4; ++n)
          s[n] = __builtin_amdgcn_mfma_f32_16x16x32_bf16(kf[kh][n], qf[kh], s[n], 0, 0, 0);
      __builtin_amdgcn_s_setprio(0);

      // causal mask (diagonal tile only); kv_in accounts for the tau permutation
      if (kt == qt) {
        int q_in = wave * 16 + l15;
#pragma unroll
        for (int n = 0; n < 4; ++n)
#pragma unroll
          for (int r = 0; r < 4; ++r) {
            int kv_in = n * 16 + (g & 1) * 8 + (g >> 1) * 4 + r;
            if (kv_in > q_in) s[n][r] = -1e30f;
          }
      }

      // lane-local online softmax (row q = l15; base-2), max3-friendly tree
      float t0 = fmaxf(fmaxf(s[0][0], s[0][1]), s[0][2]);
      float t1 = fmaxf(fmaxf(s[0][3], s[1][0]), s[1][1]);
      float t2 = fmaxf(fmaxf(s[1][2], s[1][3]), s[2][0]);
      float t3 = fmaxf(fmaxf(s[2][1], s[2][2]), s[2][3]);
      float t4 = fmaxf(fmaxf(s[3][0], s[3][1]), s[3][2]);
      float vmax = fmaxf(fmaxf(fmaxf(t0, t1), t2), fmaxf(fmaxf(t3, t4), s[3][3]));
      vmax = fmaxf(vmax, __shfl_xor(vmax, 16));
      vmax = fmaxf(vmax, __shfl_xor(vmax, 32));

      // T13 defer-max: only rescale when the row max grew by > 8 (base-2 units)
      if (!__all(vmax - mrun <= 8.f)) {
        float mnew = fmaxf(mrun, vmax);
        float a = exp2f(mrun - mnew);
        lrun *= a;
#pragma unroll
        for (int n = 0; n < 4; ++n)
#pragma unroll
          for (int r = 0; r < 4; ++r) oacc[n][r] *= a;
        mrun = mnew;
      }

      // P = exp2(S - m); accumulate lane-local partial sum (4-way split chains);
      // NO per-tile cross-lane sum -- deferred to the epilogue.
      float ps0 = 0.f, ps1 = 0.f, ps2 = 0.f, ps3 = 0.f;
#pragma unroll
      for (int n = 0; n < 4; ++n) {
        float p0 = exp2f(s[n][0] - mrun);
        float p1 = exp2f(s[n][1] - mrun);
        float p2 = exp2f(s[n][2] - mrun);
        float p3 = exp2f(s[n][3] - mrun);
        s[n][0] = p0; s[n][1] = p1; s[n][2] = p2; s[n][3] = p3;
        ps0 += p0; ps1 += p1; ps2 += p2; ps3 += p3;
      }
      lrun += (ps0 + ps1) + (ps2 + ps3);

      // O^T += V^T P^T : B-frag via cvt_pk + permlane32_swap, A-frag from Vt[cur]
      __builtin_amdgcn_s_setprio(1);
#pragma unroll
      for (int kvh = 0; kvh < 2; ++kvh) {
        const int nlo = kvh * 2, nhi = kvh * 2 + 1;
        unsigned int L0 = cvtpk_bf16(s[nlo][0], s[nlo][1]);
        unsigned int L1 = cvtpk_bf16(s[nlo][2], s[nlo][3]);
        unsigned int H0 = cvtpk_bf16(s[nhi][0], s[nhi][1]);
        unsigned int H1 = cvtpk_bf16(s[nhi][2], s[nhi][3]);
        asm volatile("v_permlane32_swap_b32 %0, %1" : "+v"(L0), "+v"(H0));
        asm volatile("v_permlane32_swap_b32 %0, %1" : "+v"(L1), "+v"(H1));
        bf16x8 pb;
        unsigned int* pw = (unsigned int*)&pb;
        pw[0] = L0; pw[1] = L1; pw[2] = H0; pw[3] = H1;

        const int ch = ((kvh * 4 + g) ^ (l15 & 7)) * 16;
#pragma unroll
        for (int n = 0; n < 4; ++n) {
          bf16x8 an = *(const bf16x8*)((const char*)(Vt[cur]) + (n * 16 + l15) * 128 + ch);
          oacc[n] = __builtin_amdgcn_mfma_f32_16x16x32_bf16(an, pb, oacc[n], 0, 0, 0);
        }
      }
      __builtin_amdgcn_s_setprio(0);

      // write prefetched V into the other buffer (perm-packed)
      if (havenext) {
        char* vtb = (char*)(Vt[cur ^ 1]);
        const unsigned int* w0 = (const unsigned int*)&v0;
        const unsigned int* w1 = (const unsigned int*)&v1;
#pragma unroll
        for (int d2 = 0; d2 < 4; ++d2) {
          int c0 = vcg * 8 + 2 * d2, c1 = c0 + 1;
          unsigned int pk0 = __builtin_amdgcn_perm(w1[d2], w0[d2], 0x05040100u);
          unsigned int pk1 = __builtin_amdgcn_perm(w1[d2], w0[d2], 0x07060302u);
          *(unsigned int*)(vtb + ((c0 * 128 + 4 * vp) ^ ((c0 & 7) << 4))) = pk0;
          *(unsigned int*)(vtb + ((c1 * 128 + 4 * vp) ^ ((c1 & 7) << 4))) = pk1;
        }
      }
    }

    // epilogue: finish the deferred sum reduce (once per q-tile), normalize,
    // transpose O^T -> O via LDS, coalesced store
    {
      float ltot = lrun;
      ltot += __shfl_xor(ltot, 16);
      ltot += __shfl_xor(ltot, 32);
      float inv = 1.f / ltot;
      char* otb = (char*)Ot;
#pragma unroll
      for (int n = 0; n < 4; ++n)
#pragma unroll
        for (int i = 0; i < 2; ++i) {
          unsigned int w2 = cvtpk_bf16(oacc[n][2 * i] * inv, oacc[n][2 * i + 1] * inv);
          int didx = n * 8 + g * 2 + i;  // d-pair index (d = 2*didx)
          int off = (wave * 16 + l15) * 128 + ((didx * 4) ^ ((l15 & 7) << 4));
          *(unsigned int*)(otb + off) = w2;
        }
      __syncthreads();
      int q = tid >> 2, seg = tid & 3;
      uint4 c0 = *(const uint4*)(otb + q * 128 + (((seg * 2) ^ (q & 7)) << 4));
      uint4 c1 = *(const uint4*)(otb + q * 128 + (((seg * 2 + 1) ^ (q & 7)) << 4));
      u16* dst = Ow + ((size_t)b * T + qt * 64 + q) * DMODEL + h * 64 + seg * 16;
      *(uint4*)dst = c0;
      *(uint4*)(dst + 8) = c1;
    }
  }
}

extern "C" void kernel_launch(void* const* d_in, const int* in_sizes, int n_in,
                              void* d_out, int out_size, void* d_ws, size_t ws_size,
                              hipStream_t stream) {
  const float* x  = (const float*)d_in[0];
  const float* Wq = (const float*)d_in[1];
  const float* bq = (const float*)d_in[2];
  const float* Wk = (const float*)d_in[3];
  const float* bk = (const float*)d_in[4];
  const float* Wv = (const float*)d_in[5];
  const float* bv = (const float*)d_in[6];
  const float* Wo = (const float*)d_in[7];
  const float* bo = (const float*)d_in[8];
  float* out = (float*)d_out;
  u16* ws = (u16*)d_ws;

  // cast x to bf16: 8M elems, 8/thread
  k_cast<<<4096, 256, 0, stream>>>(x, ws + XB_OFF);
  // transpose+cast the 4 weights
  k_transw<<<dim3(32, 32, 4), dim3(32, 8), 0, stream>>>(Wq, Wk, Wv, Wo, ws + WT_OFF);
  // QKV projections (z = 0,1,2)
  k_gemm_qkv<<<dim3(64, 8, 3), 256, 0, stream>>>(ws + XB_OFF, ws + WT_OFF, bq, bk, bv,
                                                 ws + Q_OFF, ws + K_OFF, ws + V_OFF);
  // causal flash attention (paired q-tiles, XCD-swizzled 1-D grid)
  k_attn<<<1024, 256, 0, stream>>>(ws + Q_OFF, ws + K_OFF, ws + V_OFF, ws + O_OFF);
  // output projection
  k_gemm_out<<<dim3(64, 8), 256, 0, stream>>>(ws + O_OFF, ws + WT_OFF + 3ull * DMODEL * DMODEL,
                                              bo, out);
}